// Round 1
// baseline (11.755 us; speedup 1.0000x reference)
//
#include <hip/hip_runtime.h>

// CenterLoss: loss = (1/B) * sum_b clip(||x_b - centers[labels[b]]||^2, 1e-12, 1e12)
//             + (C-1)*1e-12   (the masked zeros, clamped)
// B=2048, C=100000, D=128.

#define CL_BATCH 2048
#define CL_CLASSES 100000
#define CL_FEAT 128
#define CL_WAVES 4                      // waves per block (1 row per wave)
#define CL_BLOCKS (CL_BATCH / CL_WAVES) // 512

__global__ void __launch_bounds__(256)
cl_dist_kernel(const float* __restrict__ x,
               const int* __restrict__ labels,
               const float* __restrict__ centers,
               float* __restrict__ partial) {
    const int wave = threadIdx.x >> 6;
    const int lane = threadIdx.x & 63;
    const int b = blockIdx.x * CL_WAVES + wave;   // row index, always < 2048

    const float2* xp = reinterpret_cast<const float2*>(x + (size_t)b * CL_FEAT);
    const int lab = labels[b];
    const float2* cp = reinterpret_cast<const float2*>(centers + (size_t)lab * CL_FEAT);

    // 128 dims / 64 lanes = one float2 per lane, fully coalesced on x.
    const float2 xv = xp[lane];
    const float2 cv = cp[lane];
    const float dx = xv.x - cv.x;
    const float dy = xv.y - cv.y;
    float s = dx * dx + dy * dy;

    // wave-64 butterfly reduction
    #pragma unroll
    for (int off = 32; off > 0; off >>= 1)
        s += __shfl_down(s, off, 64);

    __shared__ float wsum[CL_WAVES];
    if (lane == 0) {
        // torch clamps each (masked) entry; the label entry is clamped too
        s = fminf(fmaxf(s, 1e-12f), 1e12f);
        wsum[wave] = s;
    }
    __syncthreads();
    if (threadIdx.x == 0) {
        float t = 0.0f;
        #pragma unroll
        for (int i = 0; i < CL_WAVES; ++i) t += wsum[i];
        partial[blockIdx.x] = t;
    }
}

__global__ void __launch_bounds__(512)
cl_reduce_kernel(const float* __restrict__ partial, float* __restrict__ out) {
    const int tid = threadIdx.x;          // 512 threads, 512 partials
    float s = partial[tid];

    #pragma unroll
    for (int off = 32; off > 0; off >>= 1)
        s += __shfl_down(s, off, 64);

    __shared__ float wsum[8];
    const int wave = tid >> 6;
    const int lane = tid & 63;
    if (lane == 0) wsum[wave] = s;
    __syncthreads();
    if (tid == 0) {
        float t = 0.0f;
        #pragma unroll
        for (int i = 0; i < 8; ++i) t += wsum[i];
        // masked zeros -> clamped to 1e-12 each: B*(C-1) of them, then /B
        const float clamp_const = (float)(CL_CLASSES - 1) * 1e-12f;
        out[0] = t / (float)CL_BATCH + clamp_const;
    }
}

extern "C" void kernel_launch(void* const* d_in, const int* in_sizes, int n_in,
                              void* d_out, int out_size, void* d_ws, size_t ws_size,
                              hipStream_t stream) {
    const float* x       = (const float*)d_in[0];
    const int*   labels  = (const int*)d_in[1];
    const float* centers = (const float*)d_in[2];
    float* out = (float*)d_out;
    float* partial = (float*)d_ws;   // 512 floats

    cl_dist_kernel<<<CL_BLOCKS, 256, 0, stream>>>(x, labels, centers, partial);
    cl_reduce_kernel<<<1, 512, 0, stream>>>(partial, out);
}